// Round 2
// baseline (505.373 us; speedup 1.0000x reference)
//
#include <hip/hip_runtime.h>

typedef _Float16 f16;
typedef __attribute__((ext_vector_type(8))) _Float16 f16x8;
typedef __attribute__((ext_vector_type(4))) float f32x4;

#define BATCH 8
#define NTOK 1025
#define DIM 768
#define HEADS 12
#define HD 64
#define MTOT (BATCH * NTOK)      // 8200
#define NQP 1088                 // q rows padded to 17*64
#define NKP 1056                 // kv rows padded to 33*32
#define NUMREL 3972

__device__ __forceinline__ int imin(int a, int b) { return a < b ? a : b; }

__device__ __forceinline__ f16x8 cvt8(const float4 a, const float4 b) {
  f16x8 r;
  r[0] = (f16)a.x; r[1] = (f16)a.y; r[2] = (f16)a.z; r[3] = (f16)a.w;
  r[4] = (f16)b.x; r[5] = (f16)b.y; r[6] = (f16)b.z; r[7] = (f16)b.w;
  return r;
}

// ---------------------------------------------------------------------------
// Kernel 1: qkv = x @ qkv_w^T + [q_bias,0,v_bias]; split into Q(scaled)/K/V^T
// 128x128 tile, BK=32, 4 waves (2x2), each wave 4x4 grid of 16x16x32 f16 MFMA.
// f32 global inputs -> f16 LDS tiles.
// ---------------------------------------------------------------------------
__global__ __launch_bounds__(256) void qkv_gemm(
    const float* __restrict__ A, const float* __restrict__ Bw,
    const float* __restrict__ q_bias, const float* __restrict__ v_bias,
    f16* __restrict__ qb, f16* __restrict__ kb, f16* __restrict__ vtb) {
  __shared__ f16 As[128][40];  // stride 40 f16 = 80B
  __shared__ f16 Bs[128][40];
  const int tid = threadIdx.x;
  const int lane = tid & 63, w = tid >> 6;
  const int wm = w >> 1, wn = w & 1;
  const int lr = lane & 15, lg = lane >> 4;
  const int tM = blockIdx.x;  // 0..64
  const int tN = blockIdx.y;  // 0..17

  f32x4 acc[4][4] = {};

  for (int kt = 0; kt < DIM; kt += 32) {
#pragma unroll
    for (int i = 0; i < 2; i++) {
      int L = tid + i * 256;
      int row = L >> 2, c8 = (L & 3) * 8;
      int gm = tM * 128 + row;
      float4 va0 = make_float4(0.f, 0.f, 0.f, 0.f), va1 = va0;
      if (gm < MTOT) {
        const float* ap = A + (size_t)gm * DIM + kt + c8;
        va0 = *(const float4*)(ap);
        va1 = *(const float4*)(ap + 4);
      }
      *(f16x8*)(&As[row][c8]) = cvt8(va0, va1);
      int gn = tN * 128 + row;  // 2304 = 18*128, always in-bounds
      const float* bp = Bw + (size_t)gn * DIM + kt + c8;
      *(f16x8*)(&Bs[row][c8]) = cvt8(*(const float4*)(bp), *(const float4*)(bp + 4));
    }
    __syncthreads();
    f16x8 af[4], bfr[4];
#pragma unroll
    for (int i = 0; i < 4; i++) {
      af[i] = *(const f16x8*)(&As[wm * 64 + i * 16 + lr][lg * 8]);
      bfr[i] = *(const f16x8*)(&Bs[wn * 64 + i * 16 + lr][lg * 8]);
    }
#pragma unroll
    for (int mi = 0; mi < 4; mi++)
#pragma unroll
      for (int ni = 0; ni < 4; ni++)
        acc[mi][ni] = __builtin_amdgcn_mfma_f32_16x16x32_f16(
            af[mi], bfr[ni], acc[mi][ni], 0, 0, 0);
    __syncthreads();
  }

  // epilogue: global col = which*768 + h*64 + dd ; which uniform per block
  const int which = tN / 6;
  const int nb = tN % 6;
#pragma unroll
  for (int mi = 0; mi < 4; mi++) {
#pragma unroll
    for (int ni = 0; ni < 4; ni++) {
      int ncol = nb * 128 + wn * 64 + ni * 16 + lr;  // 0..767
      int h = ncol >> 6, dd = ncol & 63;
      float bias = 0.f;
      if (which == 0) bias = q_bias[ncol];
      if (which == 2) bias = v_bias[ncol];
#pragma unroll
      for (int r = 0; r < 4; r++) {
        int m = tM * 128 + wm * 64 + mi * 16 + lg * 4 + r;
        if (m >= MTOT) continue;
        int b = m / NTOK;
        int t = m - b * NTOK;
        int bh = b * HEADS + h;
        float v = acc[mi][ni][r] + bias;
        if (which == 0)
          qb[((size_t)bh * NQP + t) * HD + dd] = (f16)(v * 0.125f);
        else if (which == 1)
          kb[((size_t)bh * NKP + t) * HD + dd] = (f16)v;
        else
          vtb[((size_t)bh * HD + dd) * NKP + t] = (f16)v;
      }
    }
  }
}

// ---------------------------------------------------------------------------
// Kernel 2: fused flash attention with analytic relative-position bias.
// Block = 4 waves; wave w owns 16 q rows; loop 33 kv-tiles of 32.
// ---------------------------------------------------------------------------
__device__ __forceinline__ float rpb_bias(const float* __restrict__ rpb, int qg,
                                          int kg, int h) {
  int idx;
  if (kg == 0) {
    idx = (qg == 0) ? (NUMREL - 1) : (NUMREL - 2);
  } else if (qg == 0) {
    idx = NUMREL - 3;
  } else {
    int qq = imin(qg, 1024) - 1, kk = imin(kg, 1024) - 1;
    int di = (qq >> 5) - (kk >> 5);
    int dj = (qq & 31) - (kk & 31);
    idx = (di + 31) * 63 + (dj + 31);
  }
  return rpb[idx * HEADS + h];
}

__global__ __launch_bounds__(256) void attn_kernel(
    const f16* __restrict__ qb, const f16* __restrict__ kb,
    const f16* __restrict__ vtb, const float* __restrict__ rpb,
    f16* __restrict__ ob) {
  __shared__ f16 Plds[4][16][40];  // per-wave P relayout buffer
  const int tid = threadIdx.x;
  const int lane = tid & 63, w = tid >> 6;
  const int lr = lane & 15, lg = lane >> 4;
  const int bidx = blockIdx.x;
  const int qt = bidx % 17;
  const int bh = bidx / 17;
  const int h = bh % HEADS;
  const int b = bh / HEADS;
  const int q0 = qt * 64 + w * 16;

  // Q fragments held for the whole loop; pad rows read finite garbage,
  // results discarded in the epilogue.
  const f16* qptr = qb + ((size_t)bh * NQP + q0 + lr) * HD + lg * 8;
  f16x8 aq0 = *(const f16x8*)(qptr);
  f16x8 aq1 = *(const f16x8*)(qptr + 32);

  float mrow[4], lrow[4];
  f32x4 oacc[4] = {};
#pragma unroll
  for (int r = 0; r < 4; r++) {
    mrow[r] = -1e30f;
    lrow[r] = 0.f;
  }

  const f16* kbase = kb + (size_t)bh * NKP * HD;
  const f16* vbase = vtb + (size_t)bh * HD * NKP;

  for (int kt = 0; kt < 33; kt++) {
    f32x4 s[2];
#pragma unroll
    for (int c = 0; c < 2; c++) {
      const f16* kp = kbase + ((size_t)(kt * 32 + c * 16 + lr)) * HD + lg * 8;
      f16x8 bk0 = *(const f16x8*)(kp);
      f16x8 bk1 = *(const f16x8*)(kp + 32);
      f32x4 z = {};
      z = __builtin_amdgcn_mfma_f32_16x16x32_f16(aq0, bk0, z, 0, 0, 0);
      z = __builtin_amdgcn_mfma_f32_16x16x32_f16(aq1, bk1, z, 0, 0, 0);
      s[c] = z;
    }
    // bias + mask
#pragma unroll
    for (int c = 0; c < 2; c++) {
      int kg = kt * 32 + c * 16 + lr;
#pragma unroll
      for (int r = 0; r < 4; r++) {
        int qg = q0 + lg * 4 + r;
        float sv = s[c][r] + rpb_bias(rpb, qg, kg, h);
        if (kg >= NTOK) sv = -1e30f;
        s[c][r] = sv;
      }
    }
    // online softmax (each q-row lives across a 16-lane group)
    float alpha[4];
#pragma unroll
    for (int r = 0; r < 4; r++) {
      float mx = fmaxf(s[0][r], s[1][r]);
      mx = fmaxf(mx, __shfl_xor(mx, 1));
      mx = fmaxf(mx, __shfl_xor(mx, 2));
      mx = fmaxf(mx, __shfl_xor(mx, 4));
      mx = fmaxf(mx, __shfl_xor(mx, 8));
      float mn = fmaxf(mrow[r], mx);
      alpha[r] = __expf(mrow[r] - mn);
      mrow[r] = mn;
      float p0 = __expf(s[0][r] - mn);
      float p1 = __expf(s[1][r] - mn);
      s[0][r] = p0;
      s[1][r] = p1;
      float ps = p0 + p1;
      ps += __shfl_xor(ps, 1);
      ps += __shfl_xor(ps, 2);
      ps += __shfl_xor(ps, 4);
      ps += __shfl_xor(ps, 8);
      lrow[r] = lrow[r] * alpha[r] + ps;
    }
    // P: C-layout -> A-layout via per-wave LDS slice (same-wave DS ordering)
#pragma unroll
    for (int c = 0; c < 2; c++)
#pragma unroll
      for (int r = 0; r < 4; r++)
        Plds[w][lg * 4 + r][c * 16 + lr] = (f16)s[c][r];
    f16x8 ap = *(const f16x8*)(&Plds[w][lr][lg * 8]);
    // rescale O and accumulate P@V (V^T layout -> contiguous B-frag loads)
#pragma unroll
    for (int dblk = 0; dblk < 4; dblk++) {
#pragma unroll
      for (int r = 0; r < 4; r++) oacc[dblk][r] *= alpha[r];
      const f16* vp = vbase + ((size_t)(dblk * 16 + lr)) * NKP + kt * 32 + lg * 8;
      f16x8 bv = *(const f16x8*)(vp);
      oacc[dblk] =
          __builtin_amdgcn_mfma_f32_16x16x32_f16(ap, bv, oacc[dblk], 0, 0, 0);
    }
  }
  // epilogue: write O as [B, N, H*64] (proj GEMM input layout), f16
#pragma unroll
  for (int dblk = 0; dblk < 4; dblk++) {
#pragma unroll
    for (int r = 0; r < 4; r++) {
      int qg = q0 + lg * 4 + r;
      if (qg >= NTOK) continue;
      float v = oacc[dblk][r] / lrow[r];
      ob[((size_t)(b * NTOK + qg)) * DIM + h * HD + dblk * 16 + lr] = (f16)v;
    }
  }
}

// ---------------------------------------------------------------------------
// Kernel 3: out = ob @ proj_w^T + proj_b   (A is f16 ws, B is f32 input)
// ---------------------------------------------------------------------------
__global__ __launch_bounds__(256) void proj_gemm(const f16* __restrict__ A,
                                                 const float* __restrict__ Bw,
                                                 const float* __restrict__ pb,
                                                 float* __restrict__ out) {
  __shared__ f16 As[128][40];
  __shared__ f16 Bs[128][40];
  const int tid = threadIdx.x;
  const int lane = tid & 63, w = tid >> 6;
  const int wm = w >> 1, wn = w & 1;
  const int lr = lane & 15, lg = lane >> 4;
  const int tM = blockIdx.x;  // 0..64
  const int tN = blockIdx.y;  // 0..5

  f32x4 acc[4][4] = {};

  for (int kt = 0; kt < DIM; kt += 32) {
#pragma unroll
    for (int i = 0; i < 2; i++) {
      int L = tid + i * 256;
      int row = L >> 2, c8 = (L & 3) * 8;
      int gm = tM * 128 + row;
      uint4 va = make_uint4(0u, 0u, 0u, 0u);
      if (gm < MTOT) va = *(const uint4*)(A + (size_t)gm * DIM + kt + c8);
      *(uint4*)(&As[row][c8]) = va;
      int gn = tN * 128 + row;  // 768 = 6*128, in-bounds
      const float* bp = Bw + (size_t)gn * DIM + kt + c8;
      *(f16x8*)(&Bs[row][c8]) = cvt8(*(const float4*)(bp), *(const float4*)(bp + 4));
    }
    __syncthreads();
    f16x8 af[4], bfr[4];
#pragma unroll
    for (int i = 0; i < 4; i++) {
      af[i] = *(const f16x8*)(&As[wm * 64 + i * 16 + lr][lg * 8]);
      bfr[i] = *(const f16x8*)(&Bs[wn * 64 + i * 16 + lr][lg * 8]);
    }
#pragma unroll
    for (int mi = 0; mi < 4; mi++)
#pragma unroll
      for (int ni = 0; ni < 4; ni++)
        acc[mi][ni] = __builtin_amdgcn_mfma_f32_16x16x32_f16(
            af[mi], bfr[ni], acc[mi][ni], 0, 0, 0);
    __syncthreads();
  }

#pragma unroll
  for (int mi = 0; mi < 4; mi++) {
#pragma unroll
    for (int ni = 0; ni < 4; ni++) {
      int n = tN * 128 + wn * 64 + ni * 16 + lr;
      float bias = pb[n];
#pragma unroll
      for (int r = 0; r < 4; r++) {
        int m = tM * 128 + wm * 64 + mi * 16 + lg * 4 + r;
        if (m >= MTOT) continue;
        out[(size_t)m * DIM + n] = acc[mi][ni][r] + bias;
      }
    }
  }
}

extern "C" void kernel_launch(void* const* d_in, const int* in_sizes, int n_in,
                              void* d_out, int out_size, void* d_ws,
                              size_t ws_size, hipStream_t stream) {
  const float* x = (const float*)d_in[0];
  const float* qkv_w = (const float*)d_in[1];
  const float* q_bias = (const float*)d_in[2];
  const float* v_bias = (const float*)d_in[3];
  const float* rpb = (const float*)d_in[4];
  const float* proj_w = (const float*)d_in[5];
  const float* proj_b = (const float*)d_in[6];
  // d_in[7] = rel_pos_index (int32) — reproduced analytically in-kernel
  float* out = (float*)d_out;

  f16* qb = (f16*)d_ws;
  size_t qsz = (size_t)BATCH * HEADS * NQP * HD;   // 6,684,672 elems
  size_t ksz = (size_t)BATCH * HEADS * NKP * HD;   // 6,488,064 elems
  f16* kb = qb + qsz;
  f16* vtb = kb + ksz;
  f16* ob = vtb + ksz;  // [B, NTOK, DIM] f16

  qkv_gemm<<<dim3(65, 18), 256, 0, stream>>>(x, qkv_w, q_bias, v_bias, qb, kb,
                                             vtb);
  attn_kernel<<<dim3(BATCH * HEADS * 17), 256, 0, stream>>>(qb, kb, vtb, rpb,
                                                            ob);
  proj_gemm<<<dim3(65, 6), 256, 0, stream>>>(ob, proj_w, proj_b, out);
}

// Round 3
// 490.851 us; speedup vs baseline: 1.0296x; 1.0296x over previous
//
#include <hip/hip_runtime.h>

typedef _Float16 f16;
typedef __attribute__((ext_vector_type(8))) _Float16 f16x8;
typedef __attribute__((ext_vector_type(4))) float f32x4;

#define BATCH 8
#define NTOK 1025
#define DIM 768
#define HEADS 12
#define HD 64
#define MTOT (BATCH * NTOK)      // 8200
#define NQP 1088                 // q rows padded to 17*64
#define NKP 1088                 // kv rows padded to 17*64
#define KTILES 17
#define NUMREL 3972

__device__ __forceinline__ int imin(int a, int b) { return a < b ? a : b; }

__device__ __forceinline__ f16x8 cvt8(const float4 a, const float4 b) {
  f16x8 r;
  r[0] = (f16)a.x; r[1] = (f16)a.y; r[2] = (f16)a.z; r[3] = (f16)a.w;
  r[4] = (f16)b.x; r[5] = (f16)b.y; r[6] = (f16)b.z; r[7] = (f16)b.w;
  return r;
}

// ---------------------------------------------------------------------------
// Kernel 0: precompute relative-position bias, swizzled to the exact MFMA
// C-fragment order the attention kernel consumes:
//   bias_sw[h][qt][kt][tid][c*4+r]  (f16, -30000 for masked cols kg>=NTOK)
// ---------------------------------------------------------------------------
__device__ __forceinline__ float rpb_bias(const float* __restrict__ rpb, int qg,
                                          int kg, int h) {
  int idx;
  if (kg == 0) {
    idx = (qg == 0) ? (NUMREL - 1) : (NUMREL - 2);
  } else if (qg == 0) {
    idx = NUMREL - 3;
  } else {
    int qq = imin(qg, 1024) - 1, kk = imin(kg, 1024) - 1;
    int di = (qq >> 5) - (kk >> 5);
    int dj = (qq & 31) - (kk & 31);
    idx = (di + 31) * 63 + (dj + 31);
  }
  return rpb[idx * HEADS + h];
}

__global__ __launch_bounds__(256) void bias_pre(const float* __restrict__ rpb,
                                                f16* __restrict__ bias_sw) {
  const int tile = blockIdx.x;       // 0..288
  const int h = blockIdx.y;          // 0..11
  const int qt = tile / KTILES, kt = tile % KTILES;
  const int tid = threadIdx.x;
  const int lane = tid & 63, w = tid >> 6;
  const int lr = lane & 15, lg = lane >> 4;
  f16 vals[16];
#pragma unroll
  for (int c = 0; c < 4; c++) {
#pragma unroll
    for (int r = 0; r < 4; r++) {
      int qg = qt * 64 + w * 16 + lg * 4 + r;
      int kg = kt * 64 + c * 16 + lr;
      float v = (kg >= NTOK) ? -30000.f : rpb_bias(rpb, qg, kg, h);
      vals[c * 4 + r] = (f16)v;
    }
  }
  size_t off = ((((size_t)h * KTILES + qt) * KTILES + kt) * 256 + tid) * 16;
  *(f16x8*)(bias_sw + off) = *(const f16x8*)(&vals[0]);
  *(f16x8*)(bias_sw + off + 8) = *(const f16x8*)(&vals[8]);
}

// ---------------------------------------------------------------------------
// Kernel 1: qkv = x @ qkv_w^T + [q_bias,0,v_bias]; split into Q(scaled)/K/V^T
// ---------------------------------------------------------------------------
__global__ __launch_bounds__(256) void qkv_gemm(
    const float* __restrict__ A, const float* __restrict__ Bw,
    const float* __restrict__ q_bias, const float* __restrict__ v_bias,
    f16* __restrict__ qb, f16* __restrict__ kb, f16* __restrict__ vtb) {
  __shared__ f16 As[128][40];
  __shared__ f16 Bs[128][40];
  const int tid = threadIdx.x;
  const int lane = tid & 63, w = tid >> 6;
  const int wm = w >> 1, wn = w & 1;
  const int lr = lane & 15, lg = lane >> 4;
  const int tM = blockIdx.x;  // 0..64
  const int tN = blockIdx.y;  // 0..17

  f32x4 acc[4][4] = {};

  for (int kt = 0; kt < DIM; kt += 32) {
#pragma unroll
    for (int i = 0; i < 2; i++) {
      int L = tid + i * 256;
      int row = L >> 2, c8 = (L & 3) * 8;
      int gm = tM * 128 + row;
      float4 va0 = make_float4(0.f, 0.f, 0.f, 0.f), va1 = va0;
      if (gm < MTOT) {
        const float* ap = A + (size_t)gm * DIM + kt + c8;
        va0 = *(const float4*)(ap);
        va1 = *(const float4*)(ap + 4);
      }
      *(f16x8*)(&As[row][c8]) = cvt8(va0, va1);
      int gn = tN * 128 + row;
      const float* bp = Bw + (size_t)gn * DIM + kt + c8;
      *(f16x8*)(&Bs[row][c8]) = cvt8(*(const float4*)(bp), *(const float4*)(bp + 4));
    }
    __syncthreads();
    f16x8 af[4], bfr[4];
#pragma unroll
    for (int i = 0; i < 4; i++) {
      af[i] = *(const f16x8*)(&As[wm * 64 + i * 16 + lr][lg * 8]);
      bfr[i] = *(const f16x8*)(&Bs[wn * 64 + i * 16 + lr][lg * 8]);
    }
#pragma unroll
    for (int mi = 0; mi < 4; mi++)
#pragma unroll
      for (int ni = 0; ni < 4; ni++)
        acc[mi][ni] = __builtin_amdgcn_mfma_f32_16x16x32_f16(
            af[mi], bfr[ni], acc[mi][ni], 0, 0, 0);
    __syncthreads();
  }

  const int which = tN / 6;
  const int nb = tN % 6;
#pragma unroll
  for (int mi = 0; mi < 4; mi++) {
#pragma unroll
    for (int ni = 0; ni < 4; ni++) {
      int ncol = nb * 128 + wn * 64 + ni * 16 + lr;  // 0..767
      int h = ncol >> 6, dd = ncol & 63;
      float bias = 0.f;
      if (which == 0) bias = q_bias[ncol];
      if (which == 2) bias = v_bias[ncol];
#pragma unroll
      for (int r = 0; r < 4; r++) {
        int m = tM * 128 + wm * 64 + mi * 16 + lg * 4 + r;
        if (m >= MTOT) continue;
        int b = m / NTOK;
        int t = m - b * NTOK;
        int bh = b * HEADS + h;
        float v = acc[mi][ni][r] + bias;
        if (which == 0)
          qb[((size_t)bh * NQP + t) * HD + dd] = (f16)(v * 0.125f);
        else if (which == 1)
          kb[((size_t)bh * NKP + t) * HD + dd] = (f16)v;
        else
          vtb[((size_t)bh * HD + dd) * NKP + t] = (f16)v;
      }
    }
  }
}

// ---------------------------------------------------------------------------
// Kernel 2: fused flash attention, no-max softmax (scores are O(1)-scale;
// masked cols carry -30000 bias -> exp == 0). Bias enters as MFMA C-init.
// Block = 4 waves; wave w owns 16 q rows; 17 kv-tiles of 64.
// ---------------------------------------------------------------------------
__global__ __launch_bounds__(256) void attn_kernel(
    const f16* __restrict__ qb, const f16* __restrict__ kb,
    const f16* __restrict__ vtb, const f16* __restrict__ bias_sw,
    f16* __restrict__ ob) {
  __shared__ f16 Plds[4][16][72];
  const int tid = threadIdx.x;
  const int lane = tid & 63, w = tid >> 6;
  const int lr = lane & 15, lg = lane >> 4;
  const int bidx = blockIdx.x;
  const int qt = bidx % KTILES;
  const int bh = bidx / KTILES;
  const int h = bh % HEADS;
  const int b = bh / HEADS;
  const int q0 = qt * 64 + w * 16;

  const f16* qptr = qb + ((size_t)bh * NQP + q0 + lr) * HD + lg * 8;
  f16x8 aq0 = *(const f16x8*)(qptr);
  f16x8 aq1 = *(const f16x8*)(qptr + 32);

  float lsum[4] = {0.f, 0.f, 0.f, 0.f};
  f32x4 oacc[4] = {};

  const f16* kbase = kb + (size_t)bh * NKP * HD;
  const f16* vbase = vtb + (size_t)bh * HD * NKP;
  const f16* bptr =
      bias_sw + (((size_t)(h * KTILES + qt) * KTILES) * 256 + tid) * 16;

  for (int kt = 0; kt < KTILES; kt++) {
    // bias fragments (pre-swizzled, coalesced 2x16B per lane)
    f16x8 bb0 = *(const f16x8*)(bptr + (size_t)kt * 4096);
    f16x8 bb1 = *(const f16x8*)(bptr + (size_t)kt * 4096 + 8);
    f32x4 s[4];
#pragma unroll
    for (int c = 0; c < 4; c++) {
      const f16* src = (c < 2) ? (const f16*)&bb0 : (const f16*)&bb1;
#pragma unroll
      for (int r = 0; r < 4; r++) s[c][r] = (float)src[(c & 1) * 4 + r];
    }
    // S = Q K^T + bias (bias as C-init)
#pragma unroll
    for (int c = 0; c < 4; c++) {
      const f16* kp = kbase + ((size_t)(kt * 64 + c * 16 + lr)) * HD + lg * 8;
      f16x8 bk0 = *(const f16x8*)(kp);
      f16x8 bk1 = *(const f16x8*)(kp + 32);
      s[c] = __builtin_amdgcn_mfma_f32_16x16x32_f16(aq0, bk0, s[c], 0, 0, 0);
      s[c] = __builtin_amdgcn_mfma_f32_16x16x32_f16(aq1, bk1, s[c], 0, 0, 0);
    }
    // P = exp(S); per-lane partial row sums (no cross-lane work in loop)
#pragma unroll
    for (int c = 0; c < 4; c++)
#pragma unroll
      for (int r = 0; r < 4; r++) {
        float p = __expf(s[c][r]);
        s[c][r] = p;
        lsum[r] += p;
      }
    // P: C-layout -> A-layout via per-wave LDS slice
#pragma unroll
    for (int c = 0; c < 4; c++)
#pragma unroll
      for (int r = 0; r < 4; r++)
        Plds[w][lg * 4 + r][c * 16 + lr] = (f16)s[c][r];
    f16x8 ap0 = *(const f16x8*)(&Plds[w][lr][lg * 8]);
    f16x8 ap1 = *(const f16x8*)(&Plds[w][lr][32 + lg * 8]);
    // O += P @ V
#pragma unroll
    for (int dblk = 0; dblk < 4; dblk++) {
      const f16* vp = vbase + ((size_t)(dblk * 16 + lr)) * NKP + kt * 64 + lg * 8;
      f16x8 bv0 = *(const f16x8*)(vp);
      f16x8 bv1 = *(const f16x8*)(vp + 32);
      oacc[dblk] =
          __builtin_amdgcn_mfma_f32_16x16x32_f16(ap0, bv0, oacc[dblk], 0, 0, 0);
      oacc[dblk] =
          __builtin_amdgcn_mfma_f32_16x16x32_f16(ap1, bv1, oacc[dblk], 0, 0, 0);
    }
  }
  // final row-sum reduction (once), then normalize + write
  float ltot[4];
#pragma unroll
  for (int r = 0; r < 4; r++) {
    float ls = lsum[r];
    ls += __shfl_xor(ls, 1);
    ls += __shfl_xor(ls, 2);
    ls += __shfl_xor(ls, 4);
    ls += __shfl_xor(ls, 8);
    ltot[r] = ls;
  }
#pragma unroll
  for (int dblk = 0; dblk < 4; dblk++) {
#pragma unroll
    for (int r = 0; r < 4; r++) {
      int qg = q0 + lg * 4 + r;
      if (qg >= NTOK) continue;
      float v = oacc[dblk][r] / ltot[r];
      ob[((size_t)(b * NTOK + qg)) * DIM + h * HD + dblk * 16 + lr] = (f16)v;
    }
  }
}

// ---------------------------------------------------------------------------
// Kernel 3: out = ob @ proj_w^T + proj_b
// ---------------------------------------------------------------------------
__global__ __launch_bounds__(256) void proj_gemm(const f16* __restrict__ A,
                                                 const float* __restrict__ Bw,
                                                 const float* __restrict__ pb,
                                                 float* __restrict__ out) {
  __shared__ f16 As[128][40];
  __shared__ f16 Bs[128][40];
  const int tid = threadIdx.x;
  const int lane = tid & 63, w = tid >> 6;
  const int wm = w >> 1, wn = w & 1;
  const int lr = lane & 15, lg = lane >> 4;
  const int tM = blockIdx.x;  // 0..64
  const int tN = blockIdx.y;  // 0..5

  f32x4 acc[4][4] = {};

  for (int kt = 0; kt < DIM; kt += 32) {
#pragma unroll
    for (int i = 0; i < 2; i++) {
      int L = tid + i * 256;
      int row = L >> 2, c8 = (L & 3) * 8;
      int gm = tM * 128 + row;
      uint4 va = make_uint4(0u, 0u, 0u, 0u);
      if (gm < MTOT) va = *(const uint4*)(A + (size_t)gm * DIM + kt + c8);
      *(uint4*)(&As[row][c8]) = va;
      int gn = tN * 128 + row;
      const float* bp = Bw + (size_t)gn * DIM + kt + c8;
      *(f16x8*)(&Bs[row][c8]) = cvt8(*(const float4*)(bp), *(const float4*)(bp + 4));
    }
    __syncthreads();
    f16x8 af[4], bfr[4];
#pragma unroll
    for (int i = 0; i < 4; i++) {
      af[i] = *(const f16x8*)(&As[wm * 64 + i * 16 + lr][lg * 8]);
      bfr[i] = *(const f16x8*)(&Bs[wn * 64 + i * 16 + lr][lg * 8]);
    }
#pragma unroll
    for (int mi = 0; mi < 4; mi++)
#pragma unroll
      for (int ni = 0; ni < 4; ni++)
        acc[mi][ni] = __builtin_amdgcn_mfma_f32_16x16x32_f16(
            af[mi], bfr[ni], acc[mi][ni], 0, 0, 0);
    __syncthreads();
  }

#pragma unroll
  for (int mi = 0; mi < 4; mi++) {
#pragma unroll
    for (int ni = 0; ni < 4; ni++) {
      int n = tN * 128 + wn * 64 + ni * 16 + lr;
      float bias = pb[n];
#pragma unroll
      for (int r = 0; r < 4; r++) {
        int m = tM * 128 + wm * 64 + mi * 16 + lg * 4 + r;
        if (m >= MTOT) continue;
        out[(size_t)m * DIM + n] = acc[mi][ni][r] + bias;
      }
    }
  }
}

extern "C" void kernel_launch(void* const* d_in, const int* in_sizes, int n_in,
                              void* d_out, int out_size, void* d_ws,
                              size_t ws_size, hipStream_t stream) {
  const float* x = (const float*)d_in[0];
  const float* qkv_w = (const float*)d_in[1];
  const float* q_bias = (const float*)d_in[2];
  const float* v_bias = (const float*)d_in[3];
  const float* rpb = (const float*)d_in[4];
  const float* proj_w = (const float*)d_in[5];
  const float* proj_b = (const float*)d_in[6];
  float* out = (float*)d_out;

  f16* qb = (f16*)d_ws;
  size_t qsz = (size_t)BATCH * HEADS * NQP * HD;   // 6,684,672
  size_t ksz = (size_t)BATCH * HEADS * NKP * HD;   // 6,684,672
  f16* kb = qb + qsz;
  f16* vtb = kb + ksz;
  f16* ob = vtb + ksz;                             // [B, NTOK, DIM]
  f16* bias_sw = ob + (size_t)MTOT * DIM;          // 14,204,928 elems
  // total ws: ~81.1 MB (f16)

  bias_pre<<<dim3(KTILES * KTILES, HEADS), 256, 0, stream>>>(rpb, bias_sw);
  qkv_gemm<<<dim3(65, 18), 256, 0, stream>>>(x, qkv_w, q_bias, v_bias, qb, kb,
                                             vtb);
  attn_kernel<<<dim3(BATCH * HEADS * KTILES), 256, 0, stream>>>(qb, kb, vtb,
                                                                bias_sw, ob);
  proj_gemm<<<dim3(65, 6), 256, 0, stream>>>(ob, proj_w, proj_b, out);
}

// Round 4
// 360.774 us; speedup vs baseline: 1.4008x; 1.3605x over previous
//
#include <hip/hip_runtime.h>

typedef _Float16 f16;
typedef __attribute__((ext_vector_type(8))) _Float16 f16x8;
typedef __attribute__((ext_vector_type(4))) float f32x4;

#define BATCH 8
#define NTOK 1025
#define DIM 768
#define HEADS 12
#define HD 64
#define MTOT (BATCH * NTOK)      // 8200
#define NQP 1088                 // q rows padded to 17*64
#define NKP 1088                 // kv rows padded to 17*64
#define KTILES 17
#define NUMREL 3972

__device__ __forceinline__ int imin(int a, int b) { return a < b ? a : b; }

__device__ __forceinline__ f16x8 cvt8(const float4 a, const float4 b) {
  f16x8 r;
  r[0] = (f16)a.x; r[1] = (f16)a.y; r[2] = (f16)a.z; r[3] = (f16)a.w;
  r[4] = (f16)b.x; r[5] = (f16)b.y; r[6] = (f16)b.z; r[7] = (f16)b.w;
  return r;
}

__device__ __forceinline__ void gl_lds16(const f16* g, f16* l) {
  __builtin_amdgcn_global_load_lds(
      (const __attribute__((address_space(1))) unsigned int*)g,
      (__attribute__((address_space(3))) unsigned int*)l, 16, 0, 0);
}

// ---------------------------------------------------------------------------
// Kernel 0: precompute relative-position bias, swizzled to MFMA C-frag order:
//   bias_sw[h][qt][kt][tid][c*4+r]  (f16, -30000 for masked cols kg>=NTOK)
// ---------------------------------------------------------------------------
__device__ __forceinline__ float rpb_bias(const float* __restrict__ rpb, int qg,
                                          int kg, int h) {
  int idx;
  if (kg == 0) {
    idx = (qg == 0) ? (NUMREL - 1) : (NUMREL - 2);
  } else if (qg == 0) {
    idx = NUMREL - 3;
  } else {
    int qq = imin(qg, 1024) - 1, kk = imin(kg, 1024) - 1;
    int di = (qq >> 5) - (kk >> 5);
    int dj = (qq & 31) - (kk & 31);
    idx = (di + 31) * 63 + (dj + 31);
  }
  return rpb[idx * HEADS + h];
}

__global__ __launch_bounds__(256) void bias_pre(const float* __restrict__ rpb,
                                                f16* __restrict__ bias_sw) {
  const int tile = blockIdx.x;       // 0..288
  const int h = blockIdx.y;          // 0..11
  const int qt = tile / KTILES, kt = tile % KTILES;
  const int tid = threadIdx.x;
  const int lane = tid & 63, w = tid >> 6;
  const int lr = lane & 15, lg = lane >> 4;
  f16 vals[16];
#pragma unroll
  for (int c = 0; c < 4; c++) {
#pragma unroll
    for (int r = 0; r < 4; r++) {
      int qg = qt * 64 + w * 16 + lg * 4 + r;
      int kg = kt * 64 + c * 16 + lr;
      float v = (kg >= NTOK) ? -30000.f : rpb_bias(rpb, qg, kg, h);
      vals[c * 4 + r] = (f16)v;
    }
  }
  size_t off = ((((size_t)h * KTILES + qt) * KTILES + kt) * 256 + tid) * 16;
  *(f16x8*)(bias_sw + off) = *(const f16x8*)(&vals[0]);
  *(f16x8*)(bias_sw + off + 8) = *(const f16x8*)(&vals[8]);
}

// ---------------------------------------------------------------------------
// Kernel 1: qkv = x @ qkv_w^T + [q_bias,0,v_bias]; split into Q(scaled)/K/V^T
// ---------------------------------------------------------------------------
__global__ __launch_bounds__(256) void qkv_gemm(
    const float* __restrict__ A, const float* __restrict__ Bw,
    const float* __restrict__ q_bias, const float* __restrict__ v_bias,
    f16* __restrict__ qb, f16* __restrict__ kb, f16* __restrict__ vtb) {
  __shared__ f16 As[128][40];
  __shared__ f16 Bs[128][40];
  const int tid = threadIdx.x;
  const int lane = tid & 63, w = tid >> 6;
  const int wm = w >> 1, wn = w & 1;
  const int lr = lane & 15, lg = lane >> 4;
  const int tM = blockIdx.x;  // 0..64
  const int tN = blockIdx.y;  // 0..17

  f32x4 acc[4][4] = {};

  for (int kt = 0; kt < DIM; kt += 32) {
#pragma unroll
    for (int i = 0; i < 2; i++) {
      int L = tid + i * 256;
      int row = L >> 2, c8 = (L & 3) * 8;
      int gm = tM * 128 + row;
      float4 va0 = make_float4(0.f, 0.f, 0.f, 0.f), va1 = va0;
      if (gm < MTOT) {
        const float* ap = A + (size_t)gm * DIM + kt + c8;
        va0 = *(const float4*)(ap);
        va1 = *(const float4*)(ap + 4);
      }
      *(f16x8*)(&As[row][c8]) = cvt8(va0, va1);
      int gn = tN * 128 + row;
      const float* bp = Bw + (size_t)gn * DIM + kt + c8;
      *(f16x8*)(&Bs[row][c8]) = cvt8(*(const float4*)(bp), *(const float4*)(bp + 4));
    }
    __syncthreads();
    f16x8 af[4], bfr[4];
#pragma unroll
    for (int i = 0; i < 4; i++) {
      af[i] = *(const f16x8*)(&As[wm * 64 + i * 16 + lr][lg * 8]);
      bfr[i] = *(const f16x8*)(&Bs[wn * 64 + i * 16 + lr][lg * 8]);
    }
#pragma unroll
    for (int mi = 0; mi < 4; mi++)
#pragma unroll
      for (int ni = 0; ni < 4; ni++)
        acc[mi][ni] = __builtin_amdgcn_mfma_f32_16x16x32_f16(
            af[mi], bfr[ni], acc[mi][ni], 0, 0, 0);
    __syncthreads();
  }

  const int which = tN / 6;
  const int nb = tN % 6;
#pragma unroll
  for (int mi = 0; mi < 4; mi++) {
#pragma unroll
    for (int ni = 0; ni < 4; ni++) {
      int ncol = nb * 128 + wn * 64 + ni * 16 + lr;  // 0..767
      int h = ncol >> 6, dd = ncol & 63;
      float bias = 0.f;
      if (which == 0) bias = q_bias[ncol];
      if (which == 2) bias = v_bias[ncol];
#pragma unroll
      for (int r = 0; r < 4; r++) {
        int m = tM * 128 + wm * 64 + mi * 16 + lg * 4 + r;
        if (m >= MTOT) continue;
        int b = m / NTOK;
        int t = m - b * NTOK;
        int bh = b * HEADS + h;
        float v = acc[mi][ni][r] + bias;
        if (which == 0)
          qb[((size_t)bh * NQP + t) * HD + dd] = (f16)(v * 0.125f);
        else if (which == 1)
          kb[((size_t)bh * NKP + t) * HD + dd] = (f16)v;
        else
          vtb[((size_t)bh * HD + dd) * NKP + t] = (f16)v;
      }
    }
  }
}

// ---------------------------------------------------------------------------
// Kernel 2: fused flash attention, no-max softmax, bias as MFMA C-init.
// K/V tiles staged via async global_load_lds (width 16), double-buffered,
// chunk-XOR swizzled (swizzle applied on the GLOBAL address side since the
// LDS destination is HW-fixed to base + lane*16).
// ---------------------------------------------------------------------------
__global__ __launch_bounds__(256) void attn_kernel(
    const f16* __restrict__ qb, const f16* __restrict__ kb,
    const f16* __restrict__ vtb, const f16* __restrict__ bias_sw,
    f16* __restrict__ ob) {
  __shared__ f16 Ks[2][64][64];    // 16 KB
  __shared__ f16 Vs[2][64][64];    // 16 KB (rows = d, cols = kv)
  __shared__ f16 Plds[4][16][72];  // 9 KB per-wave P relayout
  const int tid = threadIdx.x;
  const int lane = tid & 63, w = tid >> 6;
  const int lr = lane & 15, lg = lane >> 4;
  const int bidx = blockIdx.x;
  const int qt = bidx % KTILES;
  const int bh = bidx / KTILES;
  const int h = bh % HEADS;
  const int b = bh / HEADS;
  const int q0 = qt * 64 + w * 16;

  const f16* kbase = kb + (size_t)bh * NKP * HD;
  const f16* vbase = vtb + (size_t)bh * HD * NKP;
  const f16* bptr =
      bias_sw + (((size_t)(h * KTILES + qt) * KTILES) * 256 + tid) * 16;

  // staging lane geometry: each wave stages rows [w*16, w*16+16) of both tiles
  const int srow8 = lane >> 3;     // 0..7
  const int sch = lane & 7;        // 0..7
  const int swch = sch ^ srow8;    // XOR swizzle baked into global address

  // --- stage tile 0 into buffer 0 ---
#pragma unroll
  for (int pp = 0; pp < 2; pp++) {
    int p = w * 2 + pp;            // 0..7 (8 rows each)
    int row = p * 8 + srow8;
    gl_lds16(kbase + (size_t)row * HD + swch * 8, &Ks[0][p * 8][0]);
    gl_lds16(vbase + (size_t)row * NKP + swch * 8, &Vs[0][p * 8][0]);
  }

  // Q fragments (pad rows read finite garbage; discarded in epilogue)
  const f16* qptr = qb + ((size_t)bh * NQP + q0 + lr) * HD + lg * 8;
  f16x8 aq0 = *(const f16x8*)(qptr);
  f16x8 aq1 = *(const f16x8*)(qptr + 32);

  f16x8 bb0 = *(const f16x8*)(bptr);
  f16x8 bb1 = *(const f16x8*)(bptr + 8);

  float lsum[4] = {0.f, 0.f, 0.f, 0.f};
  f32x4 oacc[4] = {};
  const int sw8 = lr & 7;

  for (int kt = 0; kt < KTILES; kt++) {
    const int bi = kt & 1;
    // barrier: its structural vmcnt(0) drain completes tile kt's DMA
    __syncthreads();
    // issue tile kt+1's DMA now — flies during this iteration's compute
    if (kt + 1 < KTILES) {
#pragma unroll
      for (int pp = 0; pp < 2; pp++) {
        int p = w * 2 + pp;
        int row = p * 8 + srow8;
        gl_lds16(kbase + (size_t)((kt + 1) * 64 + row) * HD + swch * 8,
                 &Ks[bi ^ 1][p * 8][0]);
        gl_lds16(vbase + (size_t)row * NKP + (kt + 1) * 64 + swch * 8,
                 &Vs[bi ^ 1][p * 8][0]);
      }
    }
    // bias register prefetch for kt+1
    f16x8 nb0 = {}, nb1 = {};
    if (kt + 1 < KTILES) {
      nb0 = *(const f16x8*)(bptr + (size_t)(kt + 1) * 4096);
      nb1 = *(const f16x8*)(bptr + (size_t)(kt + 1) * 4096 + 8);
    }
    // S = Q K^T + bias (bias as C-init)
    f32x4 s[4];
#pragma unroll
    for (int c = 0; c < 4; c++) {
      const f16* src = (c < 2) ? (const f16*)&bb0 : (const f16*)&bb1;
#pragma unroll
      for (int r = 0; r < 4; r++) s[c][r] = (float)src[(c & 1) * 4 + r];
    }
#pragma unroll
    for (int c = 0; c < 4; c++) {
      f16x8 bk0 = *(const f16x8*)(&Ks[bi][c * 16 + lr][(lg ^ sw8) * 8]);
      f16x8 bk1 = *(const f16x8*)(&Ks[bi][c * 16 + lr][((lg + 4) ^ sw8) * 8]);
      s[c] = __builtin_amdgcn_mfma_f32_16x16x32_f16(aq0, bk0, s[c], 0, 0, 0);
      s[c] = __builtin_amdgcn_mfma_f32_16x16x32_f16(aq1, bk1, s[c], 0, 0, 0);
    }
    // P = exp(S); per-lane partial row sums
#pragma unroll
    for (int c = 0; c < 4; c++)
#pragma unroll
      for (int r = 0; r < 4; r++) {
        float p = __expf(s[c][r]);
        s[c][r] = p;
        lsum[r] += p;
      }
    // P: C-layout -> A-layout via per-wave LDS slice (no barrier needed)
#pragma unroll
    for (int c = 0; c < 4; c++)
#pragma unroll
      for (int r = 0; r < 4; r++)
        Plds[w][lg * 4 + r][c * 16 + lr] = (f16)s[c][r];
    f16x8 ap0 = *(const f16x8*)(&Plds[w][lr][lg * 8]);
    f16x8 ap1 = *(const f16x8*)(&Plds[w][lr][32 + lg * 8]);
    // O += P @ V
#pragma unroll
    for (int dblk = 0; dblk < 4; dblk++) {
      f16x8 bv0 = *(const f16x8*)(&Vs[bi][dblk * 16 + lr][(lg ^ sw8) * 8]);
      f16x8 bv1 = *(const f16x8*)(&Vs[bi][dblk * 16 + lr][((lg + 4) ^ sw8) * 8]);
      oacc[dblk] =
          __builtin_amdgcn_mfma_f32_16x16x32_f16(ap0, bv0, oacc[dblk], 0, 0, 0);
      oacc[dblk] =
          __builtin_amdgcn_mfma_f32_16x16x32_f16(ap1, bv1, oacc[dblk], 0, 0, 0);
    }
    bb0 = nb0;
    bb1 = nb1;
  }
  // final row-sum reduction, normalize, write
  float ltot[4];
#pragma unroll
  for (int r = 0; r < 4; r++) {
    float ls = lsum[r];
    ls += __shfl_xor(ls, 1);
    ls += __shfl_xor(ls, 2);
    ls += __shfl_xor(ls, 4);
    ls += __shfl_xor(ls, 8);
    ltot[r] = ls;
  }
#pragma unroll
  for (int dblk = 0; dblk < 4; dblk++) {
#pragma unroll
    for (int r = 0; r < 4; r++) {
      int qg = q0 + lg * 4 + r;
      if (qg >= NTOK) continue;
      float v = oacc[dblk][r] / ltot[r];
      ob[((size_t)(b * NTOK + qg)) * DIM + h * HD + dblk * 16 + lr] = (f16)v;
    }
  }
}

// ---------------------------------------------------------------------------
// Kernel 3: out = ob @ proj_w^T + proj_b
// ---------------------------------------------------------------------------
__global__ __launch_bounds__(256) void proj_gemm(const f16* __restrict__ A,
                                                 const float* __restrict__ Bw,
                                                 const float* __restrict__ pb,
                                                 float* __restrict__ out) {
  __shared__ f16 As[128][40];
  __shared__ f16 Bs[128][40];
  const int tid = threadIdx.x;
  const int lane = tid & 63, w = tid >> 6;
  const int wm = w >> 1, wn = w & 1;
  const int lr = lane & 15, lg = lane >> 4;
  const int tM = blockIdx.x;  // 0..64
  const int tN = blockIdx.y;  // 0..5

  f32x4 acc[4][4] = {};

  for (int kt = 0; kt < DIM; kt += 32) {
#pragma unroll
    for (int i = 0; i < 2; i++) {
      int L = tid + i * 256;
      int row = L >> 2, c8 = (L & 3) * 8;
      int gm = tM * 128 + row;
      uint4 va = make_uint4(0u, 0u, 0u, 0u);
      if (gm < MTOT) va = *(const uint4*)(A + (size_t)gm * DIM + kt + c8);
      *(uint4*)(&As[row][c8]) = va;
      int gn = tN * 128 + row;
      const float* bp = Bw + (size_t)gn * DIM + kt + c8;
      *(f16x8*)(&Bs[row][c8]) = cvt8(*(const float4*)(bp), *(const float4*)(bp + 4));
    }
    __syncthreads();
    f16x8 af[4], bfr[4];
#pragma unroll
    for (int i = 0; i < 4; i++) {
      af[i] = *(const f16x8*)(&As[wm * 64 + i * 16 + lr][lg * 8]);
      bfr[i] = *(const f16x8*)(&Bs[wn * 64 + i * 16 + lr][lg * 8]);
    }
#pragma unroll
    for (int mi = 0; mi < 4; mi++)
#pragma unroll
      for (int ni = 0; ni < 4; ni++)
        acc[mi][ni] = __builtin_amdgcn_mfma_f32_16x16x32_f16(
            af[mi], bfr[ni], acc[mi][ni], 0, 0, 0);
    __syncthreads();
  }

#pragma unroll
  for (int mi = 0; mi < 4; mi++) {
#pragma unroll
    for (int ni = 0; ni < 4; ni++) {
      int n = tN * 128 + wn * 64 + ni * 16 + lr;
      float bias = pb[n];
#pragma unroll
      for (int r = 0; r < 4; r++) {
        int m = tM * 128 + wm * 64 + mi * 16 + lg * 4 + r;
        if (m >= MTOT) continue;
        out[(size_t)m * DIM + n] = acc[mi][ni][r] + bias;
      }
    }
  }
}

extern "C" void kernel_launch(void* const* d_in, const int* in_sizes, int n_in,
                              void* d_out, int out_size, void* d_ws,
                              size_t ws_size, hipStream_t stream) {
  const float* x = (const float*)d_in[0];
  const float* qkv_w = (const float*)d_in[1];
  const float* q_bias = (const float*)d_in[2];
  const float* v_bias = (const float*)d_in[3];
  const float* rpb = (const float*)d_in[4];
  const float* proj_w = (const float*)d_in[5];
  const float* proj_b = (const float*)d_in[6];
  float* out = (float*)d_out;

  f16* qb = (f16*)d_ws;
  size_t qsz = (size_t)BATCH * HEADS * NQP * HD;   // 6,684,672
  size_t ksz = (size_t)BATCH * HEADS * NKP * HD;   // 6,684,672
  f16* kb = qb + qsz;
  f16* vtb = kb + ksz;
  f16* ob = vtb + ksz;                             // [B, NTOK, DIM]
  f16* bias_sw = ob + (size_t)MTOT * DIM;          // 14,204,928 elems

  bias_pre<<<dim3(KTILES * KTILES, HEADS), 256, 0, stream>>>(rpb, bias_sw);
  qkv_gemm<<<dim3(65, 18), 256, 0, stream>>>(x, qkv_w, q_bias, v_bias, qb, kb,
                                             vtb);
  attn_kernel<<<dim3(BATCH * HEADS * KTILES), 256, 0, stream>>>(qb, kb, vtb,
                                                                bias_sw, ob);
  proj_gemm<<<dim3(65, 6), 256, 0, stream>>>(ob, proj_w, proj_b, out);
}

// Round 5
// 316.938 us; speedup vs baseline: 1.5946x; 1.1383x over previous
//
#include <hip/hip_runtime.h>

typedef _Float16 f16;
typedef __attribute__((ext_vector_type(8))) _Float16 f16x8;
typedef __attribute__((ext_vector_type(4))) float f32x4;

#define BATCH 8
#define NTOK 1025
#define DIM 768
#define HEADS 12
#define HD 64
#define MTOT (BATCH * NTOK)      // 8200
#define MPAD 8320                // 65*128, padded rows for DMA staging
#define NQP 1088                 // q rows padded to 17*64
#define NKP 1088                 // kv rows padded to 17*64
#define KTILES 17
#define NUMREL 3972

__device__ __forceinline__ int imin(int a, int b) { return a < b ? a : b; }

__device__ __forceinline__ void gl_lds16(const f16* g, f16* l) {
  __builtin_amdgcn_global_load_lds(
      (const __attribute__((address_space(1))) unsigned int*)g,
      (__attribute__((address_space(3))) unsigned int*)l, 16, 0, 0);
}

// ---------------------------------------------------------------------------
// Kernel C: f32 -> f16 cast, 3 arrays in one launch (grid.y selects array)
// ---------------------------------------------------------------------------
__global__ __launch_bounds__(256) void cast3(const float* __restrict__ s0,
                                             f16* __restrict__ d0, int n0,
                                             const float* __restrict__ s1,
                                             f16* __restrict__ d1, int n1,
                                             const float* __restrict__ s2,
                                             f16* __restrict__ d2, int n2) {
  const float* s = (blockIdx.y == 0) ? s0 : (blockIdx.y == 1) ? s1 : s2;
  f16* d = (blockIdx.y == 0) ? d0 : (blockIdx.y == 1) ? d1 : d2;
  int n = (blockIdx.y == 0) ? n0 : (blockIdx.y == 1) ? n1 : n2;
  for (size_t i = ((size_t)blockIdx.x * 256 + threadIdx.x) * 8; i < (size_t)n;
       i += (size_t)gridDim.x * 256 * 8) {
    float4 a = *(const float4*)(s + i);
    float4 b = *(const float4*)(s + i + 4);
    f16x8 r;
    r[0] = (f16)a.x; r[1] = (f16)a.y; r[2] = (f16)a.z; r[3] = (f16)a.w;
    r[4] = (f16)b.x; r[5] = (f16)b.y; r[6] = (f16)b.z; r[7] = (f16)b.w;
    *(f16x8*)(d + i) = r;
  }
}

// ---------------------------------------------------------------------------
// Kernel 0: precompute relative-position bias, swizzled to MFMA C-frag order
// ---------------------------------------------------------------------------
__device__ __forceinline__ float rpb_bias(const float* __restrict__ rpb, int qg,
                                          int kg, int h) {
  int idx;
  if (kg == 0) {
    idx = (qg == 0) ? (NUMREL - 1) : (NUMREL - 2);
  } else if (qg == 0) {
    idx = NUMREL - 3;
  } else {
    int qq = imin(qg, 1024) - 1, kk = imin(kg, 1024) - 1;
    int di = (qq >> 5) - (kk >> 5);
    int dj = (qq & 31) - (kk & 31);
    idx = (di + 31) * 63 + (dj + 31);
  }
  return rpb[idx * HEADS + h];
}

__global__ __launch_bounds__(256) void bias_pre(const float* __restrict__ rpb,
                                                f16* __restrict__ bias_sw) {
  const int tile = blockIdx.x;       // 0..288
  const int h = blockIdx.y;          // 0..11
  const int qt = tile / KTILES, kt = tile % KTILES;
  const int tid = threadIdx.x;
  const int lane = tid & 63, w = tid >> 6;
  const int lr = lane & 15, lg = lane >> 4;
  f16 vals[16];
#pragma unroll
  for (int c = 0; c < 4; c++) {
#pragma unroll
    for (int r = 0; r < 4; r++) {
      int qg = qt * 64 + w * 16 + lg * 4 + r;
      int kg = kt * 64 + c * 16 + lr;
      float v = (kg >= NTOK) ? -30000.f : rpb_bias(rpb, qg, kg, h);
      vals[c * 4 + r] = (f16)v;
    }
  }
  size_t off = ((((size_t)h * KTILES + qt) * KTILES + kt) * 256 + tid) * 16;
  *(f16x8*)(bias_sw + off) = *(const f16x8*)(&vals[0]);
  *(f16x8*)(bias_sw + off + 8) = *(const f16x8*)(&vals[8]);
}

// ---------------------------------------------------------------------------
// Kernel 1: qkv = xh @ wh^T + [q_bias,0,v_bias]; split into Q(scaled)/K/V^T
// f16 inputs, global_load_lds width-16 staging, BK=64, chunk-XOR swizzle
// baked into the global address (LDS side is lane-linear by HW constraint).
// ---------------------------------------------------------------------------
__global__ __launch_bounds__(256) void qkv_gemm(
    const f16* __restrict__ Ah, const f16* __restrict__ Bh,
    const float* __restrict__ q_bias, const float* __restrict__ v_bias,
    f16* __restrict__ qb, f16* __restrict__ kb, f16* __restrict__ vtb) {
  __shared__ f16 As[128][64];  // 16 KB, linear rows (128 B = 8 chunks of 16 B)
  __shared__ f16 Bs[128][64];
  const int tid = threadIdx.x;
  const int lane = tid & 63, w = tid >> 6;
  const int wm = w >> 1, wn = w & 1;
  const int lr = lane & 15, lg = lane >> 4;
  const int tM = blockIdx.x;  // 0..64
  const int tN = blockIdx.y;  // 0..17
  const int r8 = lane >> 3, ch = lane & 7;
  const int swch = ch ^ r8;   // XOR swizzle on global chunk
  const int lr7 = lr & 7;

  const f16* Abase = Ah + ((size_t)tM * 128 + r8) * DIM + swch * 8;
  const f16* Bbase = Bh + ((size_t)tN * 128 + r8) * DIM + swch * 8;

  f32x4 acc[4][4] = {};

  for (int kt = 0; kt < DIM; kt += 64) {
#pragma unroll
    for (int pp = 0; pp < 4; pp++) {
      int rowb = w * 32 + pp * 8;
      gl_lds16(Abase + (size_t)rowb * DIM + kt, &As[rowb][0]);
      gl_lds16(Bbase + (size_t)rowb * DIM + kt, &Bs[rowb][0]);
    }
    __syncthreads();
#pragma unroll
    for (int ks = 0; ks < 2; ks++) {
      f16x8 af[4], bfr[4];
      int rc = ((ks * 4 + lg) ^ lr7) * 8;
#pragma unroll
      for (int i = 0; i < 4; i++) {
        af[i] = *(const f16x8*)(&As[wm * 64 + i * 16 + lr][rc]);
        bfr[i] = *(const f16x8*)(&Bs[wn * 64 + i * 16 + lr][rc]);
      }
#pragma unroll
      for (int mi = 0; mi < 4; mi++)
#pragma unroll
        for (int ni = 0; ni < 4; ni++)
          acc[mi][ni] = __builtin_amdgcn_mfma_f32_16x16x32_f16(
              af[mi], bfr[ni], acc[mi][ni], 0, 0, 0);
    }
    __syncthreads();
  }

  const int which = tN / 6;
  const int nb = tN % 6;
#pragma unroll
  for (int mi = 0; mi < 4; mi++) {
#pragma unroll
    for (int ni = 0; ni < 4; ni++) {
      int ncol = nb * 128 + wn * 64 + ni * 16 + lr;  // 0..767
      int h = ncol >> 6, dd = ncol & 63;
      float bias = 0.f;
      if (which == 0) bias = q_bias[ncol];
      if (which == 2) bias = v_bias[ncol];
#pragma unroll
      for (int r = 0; r < 4; r++) {
        int m = tM * 128 + wm * 64 + mi * 16 + lg * 4 + r;
        if (m >= MTOT) continue;
        int b = m / NTOK;
        int t = m - b * NTOK;
        int bh = b * HEADS + h;
        float v = acc[mi][ni][r] + bias;
        if (which == 0)
          qb[((size_t)bh * NQP + t) * HD + dd] = (f16)(v * 0.125f);
        else if (which == 1)
          kb[((size_t)bh * NKP + t) * HD + dd] = (f16)v;
        else
          vtb[((size_t)bh * HD + dd) * NKP + t] = (f16)v;
      }
    }
  }
}

// ---------------------------------------------------------------------------
// Kernel 2: fused flash attention (unchanged from round 4)
// ---------------------------------------------------------------------------
__global__ __launch_bounds__(256) void attn_kernel(
    const f16* __restrict__ qb, const f16* __restrict__ kb,
    const f16* __restrict__ vtb, const f16* __restrict__ bias_sw,
    f16* __restrict__ ob) {
  __shared__ f16 Ks[2][64][64];
  __shared__ f16 Vs[2][64][64];
  __shared__ f16 Plds[4][16][72];
  const int tid = threadIdx.x;
  const int lane = tid & 63, w = tid >> 6;
  const int lr = lane & 15, lg = lane >> 4;
  const int bidx = blockIdx.x;
  const int qt = bidx % KTILES;
  const int bh = bidx / KTILES;
  const int h = bh % HEADS;
  const int b = bh / HEADS;
  const int q0 = qt * 64 + w * 16;

  const f16* kbase = kb + (size_t)bh * NKP * HD;
  const f16* vbase = vtb + (size_t)bh * HD * NKP;
  const f16* bptr =
      bias_sw + (((size_t)(h * KTILES + qt) * KTILES) * 256 + tid) * 16;

  const int srow8 = lane >> 3;
  const int sch = lane & 7;
  const int swch = sch ^ srow8;

#pragma unroll
  for (int pp = 0; pp < 2; pp++) {
    int p = w * 2 + pp;
    int row = p * 8 + srow8;
    gl_lds16(kbase + (size_t)row * HD + swch * 8, &Ks[0][p * 8][0]);
    gl_lds16(vbase + (size_t)row * NKP + swch * 8, &Vs[0][p * 8][0]);
  }

  const f16* qptr = qb + ((size_t)bh * NQP + q0 + lr) * HD + lg * 8;
  f16x8 aq0 = *(const f16x8*)(qptr);
  f16x8 aq1 = *(const f16x8*)(qptr + 32);

  f16x8 bb0 = *(const f16x8*)(bptr);
  f16x8 bb1 = *(const f16x8*)(bptr + 8);

  float lsum[4] = {0.f, 0.f, 0.f, 0.f};
  f32x4 oacc[4] = {};
  const int sw8 = lr & 7;

  for (int kt = 0; kt < KTILES; kt++) {
    const int bi = kt & 1;
    __syncthreads();
    if (kt + 1 < KTILES) {
#pragma unroll
      for (int pp = 0; pp < 2; pp++) {
        int p = w * 2 + pp;
        int row = p * 8 + srow8;
        gl_lds16(kbase + (size_t)((kt + 1) * 64 + row) * HD + swch * 8,
                 &Ks[bi ^ 1][p * 8][0]);
        gl_lds16(vbase + (size_t)row * NKP + (kt + 1) * 64 + swch * 8,
                 &Vs[bi ^ 1][p * 8][0]);
      }
    }
    f16x8 nb0 = {}, nb1 = {};
    if (kt + 1 < KTILES) {
      nb0 = *(const f16x8*)(bptr + (size_t)(kt + 1) * 4096);
      nb1 = *(const f16x8*)(bptr + (size_t)(kt + 1) * 4096 + 8);
    }
    f32x4 s[4];
#pragma unroll
    for (int c = 0; c < 4; c++) {
      const f16* src = (c < 2) ? (const f16*)&bb0 : (const f16*)&bb1;
#pragma unroll
      for (int r = 0; r < 4; r++) s[c][r] = (float)src[(c & 1) * 4 + r];
    }
#pragma unroll
    for (int c = 0; c < 4; c++) {
      f16x8 bk0 = *(const f16x8*)(&Ks[bi][c * 16 + lr][(lg ^ sw8) * 8]);
      f16x8 bk1 = *(const f16x8*)(&Ks[bi][c * 16 + lr][((lg + 4) ^ sw8) * 8]);
      s[c] = __builtin_amdgcn_mfma_f32_16x16x32_f16(aq0, bk0, s[c], 0, 0, 0);
      s[c] = __builtin_amdgcn_mfma_f32_16x16x32_f16(aq1, bk1, s[c], 0, 0, 0);
    }
#pragma unroll
    for (int c = 0; c < 4; c++)
#pragma unroll
      for (int r = 0; r < 4; r++) {
        float p = __expf(s[c][r]);
        s[c][r] = p;
        lsum[r] += p;
      }
#pragma unroll
    for (int c = 0; c < 4; c++)
#pragma unroll
      for (int r = 0; r < 4; r++)
        Plds[w][lg * 4 + r][c * 16 + lr] = (f16)s[c][r];
    f16x8 ap0 = *(const f16x8*)(&Plds[w][lr][lg * 8]);
    f16x8 ap1 = *(const f16x8*)(&Plds[w][lr][32 + lg * 8]);
#pragma unroll
    for (int dblk = 0; dblk < 4; dblk++) {
      f16x8 bv0 = *(const f16x8*)(&Vs[bi][dblk * 16 + lr][(lg ^ sw8) * 8]);
      f16x8 bv1 = *(const f16x8*)(&Vs[bi][dblk * 16 + lr][((lg + 4) ^ sw8) * 8]);
      oacc[dblk] =
          __builtin_amdgcn_mfma_f32_16x16x32_f16(ap0, bv0, oacc[dblk], 0, 0, 0);
      oacc[dblk] =
          __builtin_amdgcn_mfma_f32_16x16x32_f16(ap1, bv1, oacc[dblk], 0, 0, 0);
    }
    bb0 = nb0;
    bb1 = nb1;
  }
  float ltot[4];
#pragma unroll
  for (int r = 0; r < 4; r++) {
    float ls = lsum[r];
    ls += __shfl_xor(ls, 1);
    ls += __shfl_xor(ls, 2);
    ls += __shfl_xor(ls, 4);
    ls += __shfl_xor(ls, 8);
    ltot[r] = ls;
  }
#pragma unroll
  for (int dblk = 0; dblk < 4; dblk++) {
#pragma unroll
    for (int r = 0; r < 4; r++) {
      int qg = q0 + lg * 4 + r;
      if (qg >= NTOK) continue;
      float v = oacc[dblk][r] / ltot[r];
      ob[((size_t)(b * NTOK + qg)) * DIM + h * HD + dblk * 16 + lr] = (f16)v;
    }
  }
}

// ---------------------------------------------------------------------------
// Kernel 3: out = ob @ pwh^T + proj_b ; 128x64 tile (780 blocks), BK=64,
// DMA staging + XOR swizzle as in qkv_gemm. Waves 2x2, each 64x32.
// ---------------------------------------------------------------------------
__global__ __launch_bounds__(256) void proj_gemm(const f16* __restrict__ Ah,
                                                 const f16* __restrict__ Bh,
                                                 const float* __restrict__ pb,
                                                 float* __restrict__ out) {
  __shared__ f16 As[128][64];
  __shared__ f16 Bs[64][64];
  const int tid = threadIdx.x;
  const int lane = tid & 63, w = tid >> 6;
  const int wm = w >> 1, wn = w & 1;
  const int lr = lane & 15, lg = lane >> 4;
  const int tM = blockIdx.x;  // 0..64
  const int tN = blockIdx.y;  // 0..11
  const int r8 = lane >> 3, ch = lane & 7;
  const int swch = ch ^ r8;
  const int lr7 = lr & 7;

  const f16* Abase = Ah + ((size_t)tM * 128 + r8) * DIM + swch * 8;
  const f16* Bbase = Bh + ((size_t)tN * 64 + r8) * DIM + swch * 8;

  f32x4 acc[4][2] = {};

  for (int kt = 0; kt < DIM; kt += 64) {
#pragma unroll
    for (int pp = 0; pp < 4; pp++) {
      int rowb = w * 32 + pp * 8;
      gl_lds16(Abase + (size_t)rowb * DIM + kt, &As[rowb][0]);
    }
#pragma unroll
    for (int pp = 0; pp < 2; pp++) {
      int rowb = w * 16 + pp * 8;
      gl_lds16(Bbase + (size_t)rowb * DIM + kt, &Bs[rowb][0]);
    }
    __syncthreads();
#pragma unroll
    for (int ks = 0; ks < 2; ks++) {
      f16x8 af[4], bfr[2];
      int rc = ((ks * 4 + lg) ^ lr7) * 8;
#pragma unroll
      for (int i = 0; i < 4; i++)
        af[i] = *(const f16x8*)(&As[wm * 64 + i * 16 + lr][rc]);
#pragma unroll
      for (int i = 0; i < 2; i++)
        bfr[i] = *(const f16x8*)(&Bs[wn * 32 + i * 16 + lr][rc]);
#pragma unroll
      for (int mi = 0; mi < 4; mi++)
#pragma unroll
        for (int ni = 0; ni < 2; ni++)
          acc[mi][ni] = __builtin_amdgcn_mfma_f32_16x16x32_f16(
              af[mi], bfr[ni], acc[mi][ni], 0, 0, 0);
    }
    __syncthreads();
  }

#pragma unroll
  for (int mi = 0; mi < 4; mi++) {
#pragma unroll
    for (int ni = 0; ni < 2; ni++) {
      int n = tN * 64 + wn * 32 + ni * 16 + lr;
      float bias = pb[n];
#pragma unroll
      for (int r = 0; r < 4; r++) {
        int m = tM * 128 + wm * 64 + mi * 16 + lg * 4 + r;
        if (m >= MTOT) continue;
        out[(size_t)m * DIM + n] = acc[mi][ni][r] + bias;
      }
    }
  }
}

extern "C" void kernel_launch(void* const* d_in, const int* in_sizes, int n_in,
                              void* d_out, int out_size, void* d_ws,
                              size_t ws_size, hipStream_t stream) {
  const float* x = (const float*)d_in[0];
  const float* qkv_w = (const float*)d_in[1];
  const float* q_bias = (const float*)d_in[2];
  const float* v_bias = (const float*)d_in[3];
  const float* rpb = (const float*)d_in[4];
  const float* proj_w = (const float*)d_in[5];
  const float* proj_b = (const float*)d_in[6];
  float* out = (float*)d_out;

  f16* xh = (f16*)d_ws;                       // [MPAD,768] (pad rows: poison)
  f16* wh = xh + (size_t)MPAD * DIM;          // [2304,768]
  f16* pwh = wh + (size_t)3 * DIM * DIM;      // [768,768]
  f16* qb = pwh + (size_t)DIM * DIM;
  size_t qsz = (size_t)BATCH * HEADS * NQP * HD;
  f16* kb = qb + qsz;
  f16* vtb = kb + qsz;
  f16* ob = vtb + qsz;                        // [MPAD,768] (pad rows: poison)
  f16* bias_sw = ob + (size_t)MPAD * DIM;     // 14,204,928 elems
  // total ws ≈ 98.8 MB (f16)

  cast3<<<dim3(1024, 3), 256, 0, stream>>>(
      x, xh, MTOT * DIM, qkv_w, wh, 3 * DIM * DIM, proj_w, pwh, DIM * DIM);
  bias_pre<<<dim3(KTILES * KTILES, HEADS), 256, 0, stream>>>(rpb, bias_sw);
  qkv_gemm<<<dim3(65, 18), 256, 0, stream>>>(xh, wh, q_bias, v_bias, qb, kb,
                                             vtb);
  attn_kernel<<<dim3(BATCH * HEADS * KTILES), 256, 0, stream>>>(qb, kb, vtb,
                                                                bias_sw, ob);
  proj_gemm<<<dim3(65, 12), 256, 0, stream>>>(ob, pwh, proj_b, out);
}

// Round 6
// 297.394 us; speedup vs baseline: 1.6993x; 1.0657x over previous
//
#include <hip/hip_runtime.h>

typedef _Float16 f16;
typedef __attribute__((ext_vector_type(4))) _Float16 f16x4;
typedef __attribute__((ext_vector_type(8))) _Float16 f16x8;
typedef __attribute__((ext_vector_type(4))) float f32x4;

#define BATCH 8
#define NTOK 1025
#define DIM 768
#define HEADS 12
#define HD 64
#define MTOT (BATCH * NTOK)      // 8200
#define MPAD 8320                // 65*128
#define NQP2 1152                // q rows padded to 9*128
#define NKP 1088                 // kv rows padded to 17*64
#define NUMREL 3972

__device__ __forceinline__ int imin(int a, int b) { return a < b ? a : b; }

__device__ __forceinline__ void gl_lds16(const f16* g, f16* l) {
  __builtin_amdgcn_global_load_lds(
      (const __attribute__((address_space(1))) unsigned int*)g,
      (__attribute__((address_space(3))) unsigned int*)l, 16, 0, 0);
}

// ---------------------------------------------------------------------------
// Kernel C: f32 -> f16 cast, 3 arrays in one launch
// ---------------------------------------------------------------------------
__global__ __launch_bounds__(256) void cast3(const float* __restrict__ s0,
                                             f16* __restrict__ d0, int n0,
                                             const float* __restrict__ s1,
                                             f16* __restrict__ d1, int n1,
                                             const float* __restrict__ s2,
                                             f16* __restrict__ d2, int n2) {
  const float* s = (blockIdx.y == 0) ? s0 : (blockIdx.y == 1) ? s1 : s2;
  f16* d = (blockIdx.y == 0) ? d0 : (blockIdx.y == 1) ? d1 : d2;
  int n = (blockIdx.y == 0) ? n0 : (blockIdx.y == 1) ? n1 : n2;
  for (size_t i = ((size_t)blockIdx.x * 256 + threadIdx.x) * 8; i < (size_t)n;
       i += (size_t)gridDim.x * 256 * 8) {
    float4 a = *(const float4*)(s + i);
    float4 b = *(const float4*)(s + i + 4);
    f16x8 r;
    r[0] = (f16)a.x; r[1] = (f16)a.y; r[2] = (f16)a.z; r[3] = (f16)a.w;
    r[4] = (f16)b.x; r[5] = (f16)b.y; r[6] = (f16)b.z; r[7] = (f16)b.w;
    *(f16x8*)(d + i) = r;
  }
}

// ---------------------------------------------------------------------------
// Kernel 0: bias table in TRANSPOSED-S fragment order:
//   tbl[h][kt][q 0..1087][lg 0..3][c*4+r] = bias(q, kv=kt*64+c*16+lg*4+r)
//   (f16, -30000 for masked kv >= NTOK)
// ---------------------------------------------------------------------------
__device__ __forceinline__ float rpb_bias(const float* __restrict__ rpb, int qg,
                                          int kg, int h) {
  int idx;
  if (kg == 0) {
    idx = (qg == 0) ? (NUMREL - 1) : (NUMREL - 2);
  } else if (qg == 0) {
    idx = NUMREL - 3;
  } else {
    int qq = imin(qg, 1024) - 1, kk = imin(kg, 1024) - 1;
    int di = (qq >> 5) - (kk >> 5);
    int dj = (qq & 31) - (kk & 31);
    idx = (di + 31) * 63 + (dj + 31);
  }
  return rpb[idx * HEADS + h];
}

__global__ __launch_bounds__(256) void bias_pre(const float* __restrict__ rpb,
                                                f16* __restrict__ tbl) {
  const int kt = blockIdx.x / 17;      // 0..16
  const int qb17 = blockIdx.x % 17;    // 0..16
  const int h = blockIdx.y;
  const int tid = threadIdx.x;
  const int q = qb17 * 64 + (tid >> 2);  // 0..1087
  const int lg = tid & 3;
  f16 vals[16];
#pragma unroll
  for (int c = 0; c < 4; c++)
#pragma unroll
    for (int r = 0; r < 4; r++) {
      int kv = kt * 64 + c * 16 + lg * 4 + r;
      float v = (kv >= NTOK) ? -30000.f : rpb_bias(rpb, q, kv, h);
      vals[c * 4 + r] = (f16)v;
    }
  size_t off = ((((size_t)h * 17 + kt) * NKP + q) * 4 + lg) * 16;
  *(f16x8*)(tbl + off) = *(const f16x8*)(&vals[0]);
  *(f16x8*)(tbl + off + 8) = *(const f16x8*)(&vals[8]);
}

// ---------------------------------------------------------------------------
// Kernel 1: qkv = xh @ wh^T + [q_bias,0,v_bias]; split Q(scaled)/K/V^T.
// Double-buffered DMA staging, BK=32, one barrier per iter.
// ---------------------------------------------------------------------------
__global__ __launch_bounds__(256) void qkv_gemm(
    const f16* __restrict__ Ah, const f16* __restrict__ Bh,
    const float* __restrict__ q_bias, const float* __restrict__ v_bias,
    f16* __restrict__ qb, f16* __restrict__ kb, f16* __restrict__ vtb) {
  __shared__ f16 As[2][128][32];  // 8 KB per buffer
  __shared__ f16 Bs[2][128][32];
  const int tid = threadIdx.x;
  const int lane = tid & 63, w = tid >> 6;
  const int wm = w >> 1, wn = w & 1;
  const int lr = lane & 15, lg = lane >> 4;
  const int tM = blockIdx.x;  // 0..64
  const int tN = blockIdx.y;  // 0..17
  const int rr = lane >> 2;                 // row-in-16-group
  const int swc = (lane & 3) ^ (rr & 3);    // XOR swizzle on global chunk
  const int lr3 = lr & 3;

  const f16* Ab = Ah + ((size_t)tM * 128 + rr) * DIM + swc * 8;
  const f16* Bb = Bh + ((size_t)tN * 128 + rr) * DIM + swc * 8;

#pragma unroll
  for (int pp = 0; pp < 2; pp++) {
    int p = w * 2 + pp;
    gl_lds16(Ab + (size_t)p * 16 * DIM, &As[0][p * 16][0]);
    gl_lds16(Bb + (size_t)p * 16 * DIM, &Bs[0][p * 16][0]);
  }

  f32x4 acc[4][4] = {};

  for (int kt = 0; kt < 24; kt++) {
    const int bi = kt & 1;
    __syncthreads();  // drains prev DMA (vmcnt) + prev-iter LDS reads
    if (kt + 1 < 24) {
#pragma unroll
      for (int pp = 0; pp < 2; pp++) {
        int p = w * 2 + pp;
        gl_lds16(Ab + (size_t)p * 16 * DIM + (kt + 1) * 32,
                 &As[bi ^ 1][p * 16][0]);
        gl_lds16(Bb + (size_t)p * 16 * DIM + (kt + 1) * 32,
                 &Bs[bi ^ 1][p * 16][0]);
      }
    }
    f16x8 af[4], bf[4];
#pragma unroll
    for (int i = 0; i < 4; i++) {
      af[i] = *(const f16x8*)(&As[bi][wm * 64 + i * 16 + lr][(lg ^ lr3) * 8]);
      bf[i] = *(const f16x8*)(&Bs[bi][wn * 64 + i * 16 + lr][(lg ^ lr3) * 8]);
    }
#pragma unroll
    for (int mi = 0; mi < 4; mi++)
#pragma unroll
      for (int ni = 0; ni < 4; ni++)
        acc[mi][ni] = __builtin_amdgcn_mfma_f32_16x16x32_f16(
            af[mi], bf[ni], acc[mi][ni], 0, 0, 0);
  }

  const int which = tN / 6;
  const int nb = tN % 6;
#pragma unroll
  for (int mi = 0; mi < 4; mi++) {
#pragma unroll
    for (int ni = 0; ni < 4; ni++) {
      int ncol = nb * 128 + wn * 64 + ni * 16 + lr;  // 0..767
      int h = ncol >> 6, dd = ncol & 63;
      float bias = 0.f;
      if (which == 0) bias = q_bias[ncol];
      if (which == 2) bias = v_bias[ncol];
#pragma unroll
      for (int r = 0; r < 4; r++) {
        int m = tM * 128 + wm * 64 + mi * 16 + lg * 4 + r;
        if (m >= MTOT) continue;
        int b = m / NTOK;
        int t = m - b * NTOK;
        int bh = b * HEADS + h;
        float v = acc[mi][ni][r] + bias;
        if (which == 0)
          qb[((size_t)bh * NQP2 + t) * HD + dd] = (f16)(v * 0.125f);
        else if (which == 1)
          kb[((size_t)bh * NKP + t) * HD + dd] = (f16)v;
        else
          vtb[((size_t)bh * HD + dd) * NKP + t] = (f16)v;
      }
    }
  }
}

// ---------------------------------------------------------------------------
// Kernel 2: fused flash attention v3.
// - Transposed S (S^T = K·Q^T, MFMA args swapped): per-lane P holds 4
//   consecutive kv for one q -> P relayout = 4x ds_write_b64 + b128 reads.
// - 32 q rows/wave (128/block): halves LDS-read per FLOP.
// - Bias as MFMA C-init from pre-swizzled table; no-max softmax.
// ---------------------------------------------------------------------------
__global__ __launch_bounds__(256) void attn_kernel(
    const f16* __restrict__ qb, const f16* __restrict__ kb,
    const f16* __restrict__ vtb, const f16* __restrict__ tbl,
    f16* __restrict__ ob) {
  __shared__ f16 Ks[2][64][64];    // 16 KB
  __shared__ f16 Vs[2][64][64];    // 16 KB
  __shared__ f16 Plds[4][16][72];  // 9 KB (stride 72 f16: b64-free, b128-ok)
  const int tid = threadIdx.x;
  const int lane = tid & 63, w = tid >> 6;
  const int lr = lane & 15, lg = lane >> 4;
  const int qblk = blockIdx.x % 9;
  const int bh = blockIdx.x / 9;
  const int h = bh % HEADS, b = bh / HEADS;
  const int q0 = qblk * 128 + w * 32;

  const f16* kbase = kb + (size_t)bh * NKP * HD;
  const f16* vbase = vtb + (size_t)bh * HD * NKP;

  const int srow8 = lane >> 3;
  const int swch = (lane & 7) ^ srow8;

  // stage kv-tile 0
#pragma unroll
  for (int pp = 0; pp < 2; pp++) {
    int p = w * 2 + pp;
    int row = p * 8 + srow8;
    gl_lds16(kbase + (size_t)row * HD + swch * 8, &Ks[0][p * 8][0]);
    gl_lds16(vbase + (size_t)row * NKP + swch * 8, &Vs[0][p * 8][0]);
  }

  // Q fragments: 2 groups x 2 k-halves (B-operand lane map == A map)
  f16x8 aq[2][2];
#pragma unroll
  for (int g = 0; g < 2; g++) {
    const f16* qp = qb + ((size_t)bh * NQP2 + q0 + g * 16 + lr) * HD + lg * 8;
    aq[g][0] = *(const f16x8*)(qp);
    aq[g][1] = *(const f16x8*)(qp + 32);
  }

  // bias pointers: lane's q (clamped into table for pad rows)
  const f16* bp[2];
#pragma unroll
  for (int g = 0; g < 2; g++) {
    int qt = imin(q0 + g * 16 + lr, NKP - 1);
    bp[g] = tbl + (((size_t)h * 17 * NKP + qt) * 4 + lg) * 16;
  }
  f16x8 bb[2][2];
#pragma unroll
  for (int g = 0; g < 2; g++) {
    bb[g][0] = *(const f16x8*)(bp[g]);
    bb[g][1] = *(const f16x8*)(bp[g] + 8);
  }

  float lsum[2] = {0.f, 0.f};
  f32x4 oacc[2][4] = {};
  const int sw8 = lr & 7;
  const size_t ktstride = (size_t)NKP * 64;  // f16 elems per kt slab

  for (int kt = 0; kt < 17; kt++) {
    const int bi = kt & 1;
    __syncthreads();  // drains tile-kt DMA (structural vmcnt(0))
    if (kt + 1 < 17) {
#pragma unroll
      for (int pp = 0; pp < 2; pp++) {
        int p = w * 2 + pp;
        int row = p * 8 + srow8;
        gl_lds16(kbase + (size_t)((kt + 1) * 64 + row) * HD + swch * 8,
                 &Ks[bi ^ 1][p * 8][0]);
        gl_lds16(vbase + (size_t)row * NKP + (kt + 1) * 64 + swch * 8,
                 &Vs[bi ^ 1][p * 8][0]);
      }
    }
    f16x8 nb[2][2] = {};
    if (kt + 1 < 17) {
#pragma unroll
      for (int g = 0; g < 2; g++) {
        const f16* p8 = bp[g] + (size_t)(kt + 1) * ktstride;
        nb[g][0] = *(const f16x8*)(p8);
        nb[g][1] = *(const f16x8*)(p8 + 8);
      }
    }
    // bias C-init (element c*4+r of lane's 16-chunk)
    f32x4 s[2][4];
#pragma unroll
    for (int g = 0; g < 2; g++)
#pragma unroll
      for (int c = 0; c < 4; c++) {
        const f16* src = (const f16*)&bb[g][c >> 1];
#pragma unroll
        for (int r = 0; r < 4; r++) s[g][c][r] = (float)src[(c & 1) * 4 + r];
      }
    // S^T = K·Q^T  (K as A, Q as B); K frags shared across groups
#pragma unroll
    for (int c = 0; c < 4; c++) {
      f16x8 kf0 = *(const f16x8*)(&Ks[bi][c * 16 + lr][(lg ^ sw8) * 8]);
      f16x8 kf1 = *(const f16x8*)(&Ks[bi][c * 16 + lr][((lg + 4) ^ sw8) * 8]);
      s[0][c] = __builtin_amdgcn_mfma_f32_16x16x32_f16(kf0, aq[0][0], s[0][c], 0, 0, 0);
      s[0][c] = __builtin_amdgcn_mfma_f32_16x16x32_f16(kf1, aq[0][1], s[0][c], 0, 0, 0);
      s[1][c] = __builtin_amdgcn_mfma_f32_16x16x32_f16(kf0, aq[1][0], s[1][c], 0, 0, 0);
      s[1][c] = __builtin_amdgcn_mfma_f32_16x16x32_f16(kf1, aq[1][1], s[1][c], 0, 0, 0);
    }
    // P = exp(S); lane-scalar row sums (lane's q = lr)
#pragma unroll
    for (int g = 0; g < 2; g++)
#pragma unroll
      for (int c = 0; c < 4; c++)
#pragma unroll
        for (int r = 0; r < 4; r++) {
          float p = __expf(s[g][c][r]);
          s[g][c][r] = p;
          lsum[g] += p;
        }
    // relayout: 4x b64 packed writes per group; same-wave DS order guards WAR
    f16x8 ap[2][2];
#pragma unroll
    for (int g = 0; g < 2; g++) {
#pragma unroll
      for (int c = 0; c < 4; c++) {
        f16x4 pk;
        pk[0] = (f16)s[g][c][0];
        pk[1] = (f16)s[g][c][1];
        pk[2] = (f16)s[g][c][2];
        pk[3] = (f16)s[g][c][3];
        *(f16x4*)(&Plds[w][lr][c * 16 + lg * 4]) = pk;
      }
      ap[g][0] = *(const f16x8*)(&Plds[w][lr][lg * 8]);
      ap[g][1] = *(const f16x8*)(&Plds[w][lr][32 + lg * 8]);
    }
    // O += P @ V ; V frags shared across groups
#pragma unroll
    for (int dblk = 0; dblk < 4; dblk++) {
      f16x8 vf0 = *(const f16x8*)(&Vs[bi][dblk * 16 + lr][(lg ^ sw8) * 8]);
      f16x8 vf1 = *(const f16x8*)(&Vs[bi][dblk * 16 + lr][((lg + 4) ^ sw8) * 8]);
      oacc[0][dblk] = __builtin_amdgcn_mfma_f32_16x16x32_f16(ap[0][0], vf0, oacc[0][dblk], 0, 0, 0);
      oacc[0][dblk] = __builtin_amdgcn_mfma_f32_16x16x32_f16(ap[0][1], vf1, oacc[0][dblk], 0, 0, 0);
      oacc[1][dblk] = __builtin_amdgcn_mfma_f32_16x16x32_f16(ap[1][0], vf0, oacc[1][dblk], 0, 0, 0);
      oacc[1][dblk] = __builtin_amdgcn_mfma_f32_16x16x32_f16(ap[1][1], vf1, oacc[1][dblk], 0, 0, 0);
    }
#pragma unroll
    for (int g = 0; g < 2; g++) {
      bb[g][0] = nb[g][0];
      bb[g][1] = nb[g][1];
    }
  }
  // epilogue: reduce lsum over lg groups, redistribute to C-layout rows
#pragma unroll
  for (int g = 0; g < 2; g++) {
    float ls = lsum[g];
    ls += __shfl_xor(ls, 16);
    ls += __shfl_xor(ls, 32);
    float inv[4];
#pragma unroll
    for (int r = 0; r < 4; r++) inv[r] = 1.f / __shfl(ls, lg * 4 + r);
#pragma unroll
    for (int dblk = 0; dblk < 4; dblk++)
#pragma unroll
      for (int r = 0; r < 4; r++) {
        int qg = q0 + g * 16 + lg * 4 + r;
        if (qg >= NTOK) continue;
        float v = oacc[g][dblk][r] * inv[r];
        ob[((size_t)(b * NTOK + qg)) * DIM + h * HD + dblk * 16 + lr] = (f16)v;
      }
  }
}

// ---------------------------------------------------------------------------
// Kernel 3: out = ob @ pwh^T + proj_b. 128x64 tile, BK=32, dbuf DMA staging.
// ---------------------------------------------------------------------------
__global__ __launch_bounds__(256) void proj_gemm(const f16* __restrict__ Ah,
                                                 const f16* __restrict__ Bh,
                                                 const float* __restrict__ pb,
                                                 float* __restrict__ out) {
  __shared__ f16 As[2][128][32];
  __shared__ f16 Bs[2][64][32];
  const int tid = threadIdx.x;
  const int lane = tid & 63, w = tid >> 6;
  const int wm = w >> 1, wn = w & 1;
  const int lr = lane & 15, lg = lane >> 4;
  const int tM = blockIdx.x;  // 0..64
  const int tN = blockIdx.y;  // 0..11
  const int rr = lane >> 2;
  const int swc = (lane & 3) ^ (rr & 3);
  const int lr3 = lr & 3;

  const f16* Ab = Ah + ((size_t)tM * 128 + rr) * DIM + swc * 8;
  const f16* Bb = Bh + ((size_t)tN * 64 + rr) * DIM + swc * 8;

#pragma unroll
  for (int pp = 0; pp < 2; pp++) {
    int p = w * 2 + pp;
    gl_lds16(Ab + (size_t)p * 16 * DIM, &As[0][p * 16][0]);
  }
  gl_lds16(Bb + (size_t)w * 16 * DIM, &Bs[0][w * 16][0]);

  f32x4 acc[4][2] = {};

  for (int kt = 0; kt < 24; kt++) {
    const int bi = kt & 1;
    __syncthreads();
    if (kt + 1 < 24) {
#pragma unroll
      for (int pp = 0; pp < 2; pp++) {
        int p = w * 2 + pp;
        gl_lds16(Ab + (size_t)p * 16 * DIM + (kt + 1) * 32,
                 &As[bi ^ 1][p * 16][0]);
      }
      gl_lds16(Bb + (size_t)w * 16 * DIM + (kt + 1) * 32, &Bs[bi ^ 1][w * 16][0]);
    }
    f16x8 af[4], bf[2];
#pragma unroll
    for (int i = 0; i < 4; i++)
      af[i] = *(const f16x8*)(&As[bi][wm * 64 + i * 16 + lr][(lg ^ lr3) * 8]);
#pragma unroll
    for (int i = 0; i < 2; i++)
      bf[i] = *(const f16x8*)(&Bs[bi][wn * 32 + i * 16 + lr][(lg ^ lr3) * 8]);
#pragma unroll
    for (int mi = 0; mi < 4; mi++)
#pragma unroll
      for (int ni = 0; ni < 2; ni++)
        acc[mi][ni] = __builtin_amdgcn_mfma_f32_16x16x32_f16(
            af[mi], bf[ni], acc[mi][ni], 0, 0, 0);
  }

#pragma unroll
  for (int mi = 0; mi < 4; mi++) {
#pragma unroll
    for (int ni = 0; ni < 2; ni++) {
      int n = tN * 64 + wn * 32 + ni * 16 + lr;
      float bias = pb[n];
#pragma unroll
      for (int r = 0; r < 4; r++) {
        int m = tM * 128 + wm * 64 + mi * 16 + lg * 4 + r;
        if (m >= MTOT) continue;
        out[(size_t)m * DIM + n] = acc[mi][ni][r] + bias;
      }
    }
  }
}

extern "C" void kernel_launch(void* const* d_in, const int* in_sizes, int n_in,
                              void* d_out, int out_size, void* d_ws,
                              size_t ws_size, hipStream_t stream) {
  const float* x = (const float*)d_in[0];
  const float* qkv_w = (const float*)d_in[1];
  const float* q_bias = (const float*)d_in[2];
  const float* v_bias = (const float*)d_in[3];
  const float* rpb = (const float*)d_in[4];
  const float* proj_w = (const float*)d_in[5];
  const float* proj_b = (const float*)d_in[6];
  float* out = (float*)d_out;

  f16* xh = (f16*)d_ws;                        // [MPAD,768]
  f16* wh = xh + (size_t)MPAD * DIM;           // [2304,768]
  f16* pwh = wh + (size_t)3 * DIM * DIM;       // [768,768]
  f16* qb = pwh + (size_t)DIM * DIM;           // [96,1152,64]
  f16* kb = qb + (size_t)BATCH * HEADS * NQP2 * HD;
  f16* vtb = kb + (size_t)BATCH * HEADS * NKP * HD;
  f16* ob = vtb + (size_t)BATCH * HEADS * NKP * HD;  // [MPAD,768]
  f16* tbl = ob + (size_t)MPAD * DIM;          // [12,17,1088,64]
  // total ws ≈ 99.6 MB

  cast3<<<dim3(1024, 3), 256, 0, stream>>>(
      x, xh, MTOT * DIM, qkv_w, wh, 3 * DIM * DIM, proj_w, pwh, DIM * DIM);
  bias_pre<<<dim3(17 * 17, HEADS), 256, 0, stream>>>(rpb, tbl);
  qkv_gemm<<<dim3(65, 18), 256, 0, stream>>>(xh, wh, q_bias, v_bias, qb, kb,
                                             vtb);
  attn_kernel<<<dim3(BATCH * HEADS * 9), 256, 0, stream>>>(qb, kb, vtb, tbl,
                                                           ob);
  proj_gemm<<<dim3(65, 12), 256, 0, stream>>>(ob, pwh, proj_b, out);
}